// Round 15
// baseline (1442.945 us; speedup 1.0000x reference)
//
#include <hip/hip_runtime.h>

#define HID 256
#define TLEN 1024
#define BATCH 128

typedef _Float16 half2_t __attribute__((ext_vector_type(2)));
typedef int i32x4 __attribute__((ext_vector_type(4)));

// NOTE: __has_builtin for amdgcn builtins is only true in the DEVICE pass;
// R14's unguarded #error killed the HOST pass. Guard properly:
#if defined(__HIP_DEVICE_COMPILE__)
#if !__has_builtin(__builtin_amdgcn_mfma_i32_16x16x32_i8)
#error "mfma_i32_16x16x32_i8 builtin missing on gfx950 device pass"
#endif
#endif

#define SDOT4(a, b, c) __builtin_amdgcn_sdot4((int)(a), (int)(b), (c), false)

__device__ __forceinline__ float fexp2(float x) { return __builtin_amdgcn_exp2f(x); }
__device__ __forceinline__ float frcp(float x)  { return __builtin_amdgcn_rcpf(x); }
__device__ __forceinline__ float fast_sigmoid(float x) {
  return frcp(1.0f + fexp2(-1.442695040888963f * x));
}
__device__ __forceinline__ float fast_tanh(float x) {
  float e = fexp2(2.885390081777927f * x);
  return 1.0f - 2.0f * frcp(e + 1.0f);
}
__device__ __forceinline__ float dot2acc(half2_t a, half2_t b, float c) {
  return __builtin_amdgcn_fdot2(a, b, c, false);
}

// DPP (VALU pipe). Verified on this HW R6-R13.
#define DPP_ADD_F(var, ctrl, rmask)                                            \
  var += __builtin_bit_cast(float, __builtin_amdgcn_update_dpp(                \
      0, __builtin_bit_cast(int, var), (ctrl), (rmask), 0xf, true))
#define DPP_ADD_I(var, ctrl, rmask)                                            \
  var += __builtin_amdgcn_update_dpp(0, (var), (ctrl), (rmask), 0xf, true)

__device__ __forceinline__ float wave_sum63_f(float p) {
  DPP_ADD_F(p, 0x111, 0xf);
  DPP_ADD_F(p, 0x112, 0xf);
  DPP_ADD_F(p, 0x114, 0xf);
  DPP_ADD_F(p, 0x118, 0xf);
  DPP_ADD_F(p, 0x142, 0xa);
  DPP_ADD_F(p, 0x143, 0xc);
  return p;
}
__device__ __forceinline__ int wave_sum63_i(int p) {
  DPP_ADD_I(p, 0x111, 0xf);
  DPP_ADD_I(p, 0x112, 0xf);
  DPP_ADD_I(p, 0x114, 0xf);
  DPP_ADD_I(p, 0x118, 0xf);
  DPP_ADD_I(p, 0x142, 0xa);
  DPP_ADD_I(p, 0x143, 0xc);
  return p;
}

// ---- prep 1: per-row scales for W_hh + i8 pack of Wb_h ----
__global__ void prep_scales(const float* __restrict__ W_hh,
                            const float* __restrict__ Wb_h,
                            float* __restrict__ scales,
                            unsigned* __restrict__ wbq,
                            float* __restrict__ wbscale) {
  const int r = blockIdx.x * 256 + threadIdx.x;   // 0..1023
  if (r < 768) {
    const float* row = W_hh + (size_t)r * HID;
    float amax = 0.0f;
    for (int k = 0; k < HID; ++k) amax = fmaxf(amax, fabsf(row[k]));
    scales[r] = fmaxf(amax, 1e-20f) / 127.0f;
  } else if (r < 832) {
    float amax = 0.0f;
    for (int k = 0; k < HID; ++k) amax = fmaxf(amax, fabsf(Wb_h[k]));
    amax = fmaxf(amax, 1e-20f);
    const float inv = 127.0f / amax;
    const int i = r - 768;
    unsigned bb = 0;
#pragma unroll
    for (int e = 0; e < 4; ++e) {
      int qv = (int)rintf(Wb_h[4 * i + e] * inv);
      bb |= (unsigned)(qv & 0xff) << (8 * e);
    }
    wbq[i] = bb;
    if (i == 0) wbscale[0] = (amax / 127.0f) * (1.0f / 127.0f);
  }
}

// ---- prep 2: pack W_hh into MFMA A-fragments (i8, per-row scale).
// Wave w, tile rt (g=rt>>2, jb=rt&3), k-slice s, lane l:
//   row = 256*g + 64*w + 16*jb + (l&15); k0 = 32*s + 8*(l>>4)
//   aq[(w*96 + rt*8 + s)*64 + l] = 8 bytes row[k0..k0+7] quantized (LE).
__global__ void pack_a(const float* __restrict__ W_hh,
                       const float* __restrict__ scales,
                       unsigned long long* __restrict__ aq) {
  const int idx = blockIdx.x * 256 + threadIdx.x;   // [0, 24576)
  const int w = idx / 6144;
  const int rem = idx - w * 6144;
  const int i = rem >> 6;           // rt*8+s
  const int l = rem & 63;
  const int rt = i >> 3, s = i & 7;
  const int g = rt >> 2, jb = rt & 3;
  const int row = 256 * g + 64 * w + 16 * jb + (l & 15);
  const int k0 = 32 * s + 8 * (l >> 4);
  const float inv = frcp(scales[row]);   // = 127/amax
  const float* rp = W_hh + (size_t)row * HID + k0;
  unsigned lo = 0, hi = 0;
#pragma unroll
  for (int e = 0; e < 4; ++e) {
    int qv = (int)rintf(rp[e] * inv);
    lo |= (unsigned)(qv & 0xff) << (8 * e);
  }
#pragma unroll
  for (int e = 0; e < 4; ++e) {
    int qv = (int)rintf(rp[4 + e] * inv);
    hi |= (unsigned)(qv & 0xff) << (8 * e);
  }
  aq[idx] = ((unsigned long long)hi << 32) | lo;
}

// One block per batch element, 256 threads (4 waves, 1 wave/SIMD).
// R15 = R14 (host-pass #error fixed): gh matvec on the MFMA pipe
// (v_mfma_i32_16x16x32_i8). R13 was VALU-issue-bound: sdot4 = 1 MAC/cyc/lane
// (768 cyc/SIMD/step) + ~250 cyc AGPR-parking readback tax. MFMA: 96
// instr/wave/step (~470 cyc on the separate matrix pipe), A operands read
// DIRECTLY from AGPRs (parking becomes free), gates/beta VALU issues in the
// MFMA gaps (m114 co-scheduling). B = h in column 0 only (lanes 0/16/32/48
// carry the four 8-byte k-chunks of each 32-k slice; other lanes zero).
// D extraction via wave-private LDS (C/D: col=lane&15, row=(lane>>4)*4+reg;
// A: row m=lane&15, k=(lane>>4)*8+j — guide-verified mappings).
// Integer math identical to R13's sdot4 -> expected bit-identical output.
__global__
__attribute__((amdgpu_flat_work_group_size(256, 256)))
__attribute__((amdgpu_waves_per_eu(1, 1)))
void momgru_persistent(const float* __restrict__ x,
                       const float* __restrict__ W_ih,
                       const float* __restrict__ b_ih,
                       const float* __restrict__ b_hh,
                       const float* __restrict__ Wb_x,
                       const float* __restrict__ b_beta,
                       const float* __restrict__ s_ptr,
                       const float* __restrict__ W_head,
                       const float* __restrict__ b_head,
                       const unsigned long long* __restrict__ aq,
                       const float* __restrict__ scales,
                       const unsigned* __restrict__ wbq,
                       const float* __restrict__ wbscale,
                       float* __restrict__ out)  // [0,128) head, [128,128+B*T) betas
{
  const int b    = blockIdx.x;
  const int tid  = threadIdx.x;   // == dim d
  const int lane = tid & 63;
  const int wv   = tid >> 6;      // wave index 0..3

  __shared__ unsigned hq[2][64];    // 512 B: h as i8, double-buffered
  __shared__ int      gd[4 * 192];  // 3 KB: per-wave D extraction (r,z,n x 64)
  __shared__ float    red[4];       // head reduce

  // ---- weights: 96 A-fragments (i64/lane) -> AGPR-resident, MFMA-readable ----
  long long wa[96];
#pragma unroll
  for (int i = 0; i < 96; ++i)
    wa[i] = (long long)aq[(size_t)(wv * 96 + i) * 64 + lane];

  // ---- per-thread constants (s folded into input projection) ----
  const float sv = s_ptr[0];
  const half2_t wih_r = half2_t{(_Float16)(sv * W_ih[2 * tid]),             (_Float16)(sv * W_ih[2 * tid + 1])};
  const half2_t wih_z = half2_t{(_Float16)(sv * W_ih[2 * (HID + tid)]),     (_Float16)(sv * W_ih[2 * (HID + tid) + 1])};
  const half2_t wih_n = half2_t{(_Float16)(sv * W_ih[2 * (2 * HID + tid)]), (_Float16)(sv * W_ih[2 * (2 * HID + tid) + 1])};
  const float bih_r = sv * b_ih[tid], bih_z = sv * b_ih[HID + tid], bih_n = sv * b_ih[2 * HID + tid];
  const float bhh_r = b_hh[tid], bhh_z = b_hh[HID + tid], bhh_n = b_hh[2 * HID + tid];
  const float sc_r = scales[tid] * (1.0f / 127.0f);
  const float sc_z = scales[HID + tid] * (1.0f / 127.0f);
  const float sc_n = scales[2 * HID + tid] * (1.0f / 127.0f);
  const half2_t wbx2 = half2_t{(_Float16)Wb_x[0], (_Float16)Wb_x[1]};
  const float bbeta = b_beta[0];
  const unsigned wbq_l = wbq[lane];
  const float wbsc = wbscale[0];

  // ---- init ----
  if (tid < 128) reinterpret_cast<unsigned*>(hq)[tid] = 0u;
  if (tid < 4) red[tid] = 0.0f;
  float h_old = 0.0f, vr = 0.0f, vz = 0.0f, vn = 0.0f;
  float* betas = out + BATCH;
  const float2* xg2 = reinterpret_cast<const float2*>(x + (size_t)b * TLEN * 2);
  float2 xv = xg2[0];
  const bool bact = (lane & 15) == 0;       // B-carrier lanes 0,16,32,48
  const int  boff = (lane >> 4) * 8;        // their k-byte offset within a slice
  __syncthreads();

  int cur = 0;
  for (int t = 0; t < TLEN; ++t) {
    // ---- A) per-wave hWb from h_{t-1} i8 words (R13 scheme) ----
    const unsigned hw_l = reinterpret_cast<const unsigned*>(hq[cur])[lane];
    int hwb_i = SDOT4(hw_l, wbq_l, 0);
    hwb_i = wave_sum63_i(hwb_i);

    // ---- B) B-fragments: h column 0; lanes 0/16/32/48 carry k-slices ----
    const char* hbytes = reinterpret_cast<const char*>(hq[cur]);
    long long B[8];
#pragma unroll
    for (int s = 0; s < 8; ++s) {
      long long v = 0;
      if (bact) v = *reinterpret_cast<const long long*>(hbytes + 32 * s + boff);
      B[s] = v;
    }

    // ---- C) 12 row-tiles x 8 k-slices of MFMA (matrix pipe) ----
    i32x4 acc[12];
#pragma unroll
    for (int rt = 0; rt < 12; ++rt) {
      i32x4 c = {0, 0, 0, 0};
#pragma unroll
      for (int s = 0; s < 8; ++s)
        c = __builtin_amdgcn_mfma_i32_16x16x32_i8(wa[rt * 8 + s], B[s], c, 0, 0, 0);
      acc[rt] = c;
    }

    // ---- D) extract column 0: lane 16q holds rows 4q..4q+3 in regs 0..3 ----
    if (bact) {
      const int q4 = (lane >> 4) * 4;
#pragma unroll
      for (int rt = 0; rt < 12; ++rt) {
        const int g = rt >> 2, jb = rt & 3;
        *reinterpret_cast<i32x4*>(&gd[wv * 192 + g * 64 + jb * 16 + q4]) = acc[rt];
      }
    }
    __syncthreads();   // gd visibility before per-lane reads
    const int ar = gd[wv * 192 + lane];
    const int az = gd[wv * 192 + 64 + lane];
    const int an = gd[wv * 192 + 128 + lane];

    // ---- E) beta + momentum + gates ----
    const float hWb = (float)__builtin_amdgcn_readlane(hwb_i, 63) * wbsc;
    const half2_t x2 = half2_t{(_Float16)xv.x, (_Float16)xv.y};
    xv = xg2[(t + 1 < TLEN) ? t + 1 : t];
    const float beta = fast_sigmoid(dot2acc(x2, wbx2, hWb + bbeta));
    vr = beta * vr + dot2acc(x2, wih_r, bih_r);
    vz = beta * vz + dot2acc(x2, wih_z, bih_z);
    vn = beta * vn + dot2acc(x2, wih_n, bih_n);

    const float r = fast_sigmoid(vr + (float)ar * sc_r + bhh_r);
    const float z = fast_sigmoid(vz + (float)az * sc_z + bhh_z);
    const float n = fast_tanh(vn + r * ((float)an * sc_n + bhh_n));
    h_old = (1.0f - z) * n + z * h_old;

    // ---- F) quantize h -> i8, one byte store per thread ----
    const int nxt = cur ^ 1;
    const int qb = (int)rintf(h_old * 127.0f);
    reinterpret_cast<unsigned char*>(hq[nxt])[tid] = (unsigned char)(qb & 0xff);

    if (tid == 0) betas[(size_t)b * TLEN + t] = beta;

    __syncthreads();   // hq[nxt] complete before next step reads it
    cur = nxt;
  }

  // ---- head ----
  float hp = h_old * W_head[tid];
  hp = wave_sum63_f(hp);
  if (lane == 63) red[wv] = hp;
  __syncthreads();
  if (tid == 0) out[b] = red[0] + red[1] + red[2] + red[3] + b_head[0];
}

extern "C" void kernel_launch(void* const* d_in, const int* in_sizes, int n_in,
                              void* d_out, int out_size, void* d_ws, size_t ws_size,
                              hipStream_t stream) {
  const float* x      = (const float*)d_in[0];
  const float* W_ih   = (const float*)d_in[1];
  const float* W_hh   = (const float*)d_in[2];
  const float* b_ih   = (const float*)d_in[3];
  const float* b_hh   = (const float*)d_in[4];
  const float* Wb_x   = (const float*)d_in[5];
  const float* Wb_h   = (const float*)d_in[6];
  const float* b_beta = (const float*)d_in[7];
  const float* s      = (const float*)d_in[8];
  const float* W_head = (const float*)d_in[9];
  const float* b_head = (const float*)d_in[10];
  float* out = (float*)d_out;

  char* wsb = (char*)d_ws;
  unsigned long long* aq = (unsigned long long*)wsb;   // 24576*8 = 196608 B
  float*    scales  = (float*)(wsb + 196608);          // 3072 B
  unsigned* wbq     = (unsigned*)(wsb + 199680);       // 256 B
  float*    wbscale = (float*)(wsb + 199936);          // 4 B

  prep_scales<<<dim3(4), dim3(256), 0, stream>>>(W_hh, Wb_h, scales, wbq, wbscale);
  pack_a<<<dim3(96), dim3(256), 0, stream>>>(W_hh, scales, aq);
  momgru_persistent<<<dim3(BATCH), dim3(256), 0, stream>>>(
      x, W_ih, b_ih, b_hh, Wb_x, b_beta, s, W_head, b_head,
      (const unsigned long long*)aq, (const float*)scales,
      (const unsigned*)wbq, (const float*)wbscale, out);
}